// Round 9
// baseline (1677.287 us; speedup 1.0000x reference)
//
#include <hip/hip_runtime.h>
#include <math.h>
#include <stdint.h>

#define BATCH 128
#define SLEN  8000
#define HID   64
#define CHUNK 64                  // steps per fc flush; 8000 = 125 * 64
#define NCHUNK (SLEN / CHUNK)     // 125
#define ROWSTRIDE 68              // floats; row = 272 B, 16B-aligned
#define ROWBYTES  (ROWSTRIDE * 4) // 272

__device__ __forceinline__ float fast_exp2(float x) { return __builtin_amdgcn_exp2f(x); }
__device__ __forceinline__ float fast_rcp(float x)  { return __builtin_amdgcn_rcpf(x); }

__device__ __forceinline__ float bcast_lane(float v, int lane) {
    return __int_as_float(__builtin_amdgcn_readlane(__float_as_int(v), lane));
}

// tanh(x) = sign(x) * (e - 1)/(e + 1), e = 2^(2|x|*log2 e)   (UNCHANGED - bitwise)
__device__ __forceinline__ float tanh_fast(float x) {
    float ax = fabsf(x);
    float z  = fminf(ax * 2.8853900817779268f, 30.0f);
    float e  = fast_exp2(z);
    float r  = (e - 1.0f) * fast_rcp(e + 1.0f);
    return x < 0.0f ? -r : r;
}

__device__ __forceinline__ float sigmoid_fast(float x) {
    float z = fminf(fmaxf(-x * 1.4426950408889634f, -60.0f), 60.0f);
    float e = fast_exp2(z);
    return fast_rcp(1.0f + e);
}

// PIPE-BALANCED broadcast. R7/R8 showed the step end is gated by the DS pipe
// streaming 16 ds_read_b128 (~12 cyc each) that can't start until the
// tanh->ds_write completes. Readlane consumes the h REGISTER (available
// before the write), so a 16-j readlane section is the only work that fills
// the post-tanh DS-dead window — and it removes 4 reads from the gating pipe.
//   j = 0..15 : 16 v_readlane + 8 pk_fma (SGPR pairs)   [window filler]
//   j = 16..63: 12 ds_read_b128 + 24 pk_fma             [DS stream -25%]
// Chain membership/order identical to R5/R7 -> bitwise-identical output.

#define RD(V, O) asm volatile("ds_read_b128 %0, %1 offset:" #O \
                              : "=v"(V) : "v"(rdaddr))

#define PKV(ACC, W2, H2) asm volatile("v_pk_fma_f32 %0, %1, %2, %0" \
                                      : "+v"(ACC) : "v"(W2), "v"(H2))

// j<16: broadcast via readlane into an SGPR pair, packed FMA off it.
#define PK_RL(J0, J1, ACC, WPK)                                             \
    asm volatile("v_readlane_b32 s60, %1, " #J0 "\n\t"                      \
                 "v_readlane_b32 s61, %1, " #J1 "\n\t"                      \
                 "v_pk_fma_f32 %0, %2, s[60:61], %0"                        \
                 : "+v"(ACC) : "v"(h), "v"(WPK) : "s60", "s61")

#define LO(V) (*(const float2*)&(V))
#define HI(V) (*((const float2*)&(V) + 1))

#define WAITSB(N) do {                                            \
    asm volatile("s_waitcnt lgkmcnt(" #N ")" ::: "memory");       \
    __builtin_amdgcn_sched_barrier(0);                            \
} while (0)

// Steady-state DS ops in flight at the first wait: prev step's write + 12
// reads = 13.  WAITSB(8) => >=5 retired = write + r1..r4  -> j=16..31 safe.
// WAITSB(4) => write + r1..r8 -> j=32..47.  WAITSB(0) => all -> j=48..63.
#define STEP(R_) do {                                                        \
    float4 t1,t2,t3,t4,t5,t6,t7,t8,t9,tA,tB,tC;                              \
    RD(t1, 64);  RD(t2, 80);  RD(t3, 96);  RD(t4, 112);                      \
    RD(t5, 128); RD(t6, 144); RD(t7, 160); RD(t8, 176);                      \
    RD(t9, 192); RD(tA, 208); RD(tB, 224); RD(tC, 240);                      \
    float xv = bcast_lane(xcur, R_);                                         \
    float2 a01 = make_float2(fmaf(wih, xv, bias), 0.0f);                     \
    float2 a23 = make_float2(0.0f, 0.0f);                                    \
    /* j = 0..15 off the h register — fills the DS-dead window */            \
    PK_RL( 0,  1, a01, wpair[0]);  PK_RL( 2,  3, a23, wpair[1]);             \
    PK_RL( 4,  5, a01, wpair[2]);  PK_RL( 6,  7, a23, wpair[3]);             \
    PK_RL( 8,  9, a01, wpair[4]);  PK_RL(10, 11, a23, wpair[5]);             \
    PK_RL(12, 13, a01, wpair[6]);  PK_RL(14, 15, a23, wpair[7]);             \
    WAITSB(8);                                                               \
    PKV(a01, wpair[8],  LO(t1)); PKV(a23, wpair[9],  HI(t1));                \
    PKV(a01, wpair[10], LO(t2)); PKV(a23, wpair[11], HI(t2));                \
    PKV(a01, wpair[12], LO(t3)); PKV(a23, wpair[13], HI(t3));                \
    PKV(a01, wpair[14], LO(t4)); PKV(a23, wpair[15], HI(t4));                \
    WAITSB(4);                                                               \
    PKV(a01, wpair[16], LO(t5)); PKV(a23, wpair[17], HI(t5));                \
    PKV(a01, wpair[18], LO(t6)); PKV(a23, wpair[19], HI(t6));                \
    PKV(a01, wpair[20], LO(t7)); PKV(a23, wpair[21], HI(t7));                \
    PKV(a01, wpair[22], LO(t8)); PKV(a23, wpair[23], HI(t8));                \
    WAITSB(0);                                                               \
    PKV(a01, wpair[24], LO(t9)); PKV(a23, wpair[25], HI(t9));                \
    PKV(a01, wpair[26], LO(tA)); PKV(a23, wpair[27], HI(tA));                \
    PKV(a01, wpair[28], LO(tB)); PKV(a23, wpair[29], HI(tB));                \
    PKV(a01, wpair[30], LO(tC)); PKV(a23, wpair[31], HI(tC));                \
    float aa = (a01.x + a01.y) + (a23.x + a23.y);                            \
    h = tanh_fast(aa);                                                       \
    asm volatile("ds_write_b32 %0, %1" :: "v"(wraddr), "v"(h) : "memory");   \
} while (0)

__global__ __launch_bounds__(64) void rnn_balanced_kernel(
    const float* __restrict__ x,      // [B, S]
    const float* __restrict__ W_ih,   // [H, 1]
    const float* __restrict__ b_ih,   // [H]
    const float* __restrict__ W_hh,   // [H, H]
    const float* __restrict__ b_hh,   // [H]
    const float* __restrict__ fc_w,   // [2, H]
    const float* __restrict__ fc_b,   // [2]
    float* __restrict__ out)          // [B]
{
    __shared__ float hbuf[CHUNK * ROWSTRIDE];   // 64 rows of h history

    const int lane = threadIdx.x;               // == hidden index i
    const int b    = blockIdx.x;
    const float* xrow = x + (size_t)b * SLEN;

    // Lane i holds W_hh row i as float2 pairs:
    //   wpair[2q]   = (w[4q],   w[4q+1])  -> a01 chain   (q = 0..15)
    //   wpair[2q+1] = (w[4q+2], w[4q+3])  -> a23 chain
    float2 wpair[32];
    #pragma unroll
    for (int q = 0; q < 16; ++q) {
        float4 t = ((const float4*)(W_hh + lane * HID))[q];
        wpair[2*q]   = make_float2(t.x, t.y);
        wpair[2*q+1] = make_float2(t.z, t.w);
    }
    const float wih  = W_ih[lane];
    const float bias = b_ih[lane] + b_hh[lane];
    const float fcb0 = fc_b[0], fcb1 = fc_b[1];

    float h = 0.0f;                 // lane i holds h[i] (RL source + LDS write)
    float num = 0.0f, den = 0.0f;

    // LDS byte addresses (low 32 bits of a generic LDS pointer = byte offset)
    const uint32_t hb    = (uint32_t)(uintptr_t)&hbuf[0];
    const uint32_t lane4 = (uint32_t)(lane * 4);

    // h_{-1} = 0 -> row 63 (read by step r=0 of chunk 0); ordered with asm reads
    {
        float z0 = 0.0f;
        uint32_t ia = hb + 63 * ROWBYTES + lane4;
        asm volatile("ds_write_b32 %0, %1" :: "v"(ia), "v"(z0) : "memory");
    }

    float xv_next = xrow[lane];     // chunk 0's x values (one per lane)

    #pragma unroll 1
    for (int c = 0; c < NCHUNK; ++c) {
        float xcur = xv_next;
        // prefetch next chunk's x (off critical path; clamp index for last chunk)
        int nidx = (c + 1 < NCHUNK) ? (c + 1) * CHUNK + lane : lane;
        xv_next = xrow[nidx];

        uint32_t rdaddr = hb + 63 * ROWBYTES;   // step 0 reads row 63
        uint32_t wraddr = hb + lane4;           // step 0 writes row 0

        #pragma unroll 4
        for (int r = 0; r < CHUNK; ++r) {
            STEP(r);
            rdaddr = wraddr - lane4;            // next step reads row r
            wraddr += ROWBYTES;
        }
        __syncthreads();   // drains lgkm (incl. last write); hbuf complete

        // fc head for the chunk: lane processes row `lane` (1 timestep per lane)
        {
            const float4* rp = (const float4*)(hbuf + lane * ROWSTRIDE);
            float d0 = 0.f, d1 = 0.f;
            #pragma unroll
            for (int q = 0; q < 16; ++q) {
                float4 hv = rp[q];
                float4 f0 = ((const float4*)fc_w)[q];          // uniform -> s_load
                float4 f1 = ((const float4*)(fc_w + HID))[q];
                d0 += hv.x * f0.x + hv.y * f0.y + hv.z * f0.z + hv.w * f0.w;
                d1 += hv.x * f1.x + hv.y * f1.y + hv.z * f1.z + hv.w * f1.w;
            }
            float sel = sigmoid_fast(d0 + fcb0);
            float sco = sigmoid_fast(d1 + fcb1);
            num = fmaf(sco, sel, num);
            den += sel;
        }
        __syncthreads();   // hbuf reads done before next chunk overwrites
    }

    // Final cross-lane reduction of (num, den)
    #pragma unroll
    for (int off = 32; off > 0; off >>= 1) {
        num += __shfl_down(num, off);
        den += __shfl_down(den, off);
    }
    if (lane == 0) out[b] = num / den;
}

extern "C" void kernel_launch(void* const* d_in, const int* in_sizes, int n_in,
                              void* d_out, int out_size, void* d_ws, size_t ws_size,
                              hipStream_t stream) {
    const float* x    = (const float*)d_in[0];
    const float* W_ih = (const float*)d_in[1];
    const float* b_ih = (const float*)d_in[2];
    const float* W_hh = (const float*)d_in[3];
    const float* b_hh = (const float*)d_in[4];
    const float* fc_w = (const float*)d_in[5];
    const float* fc_b = (const float*)d_in[6];
    float* out = (float*)d_out;

    rnn_balanced_kernel<<<BATCH, 64, 0, stream>>>(x, W_ih, b_ih, W_hh, b_hh,
                                                  fc_w, fc_b, out);
}

// Round 10
// 1524.683 us; speedup vs baseline: 1.1001x; 1.1001x over previous
//
#include <hip/hip_runtime.h>
#include <math.h>
#include <stdint.h>

#define BATCH 128
#define SLEN  8000
#define HID   64
#define CHUNK 64                  // steps per fc flush; 8000 = 125 * 64
#define NCHUNK (SLEN / CHUNK)     // 125
#define ROWSTRIDE 68              // floats; row = 272 B, 16B-aligned
#define ROWBYTES  (ROWSTRIDE * 4) // 272

__device__ __forceinline__ float fast_exp2(float x) { return __builtin_amdgcn_exp2f(x); }
__device__ __forceinline__ float fast_rcp(float x)  { return __builtin_amdgcn_rcpf(x); }

__device__ __forceinline__ float bcast_lane(float v, int lane) {
    return __int_as_float(__builtin_amdgcn_readlane(__float_as_int(v), lane));
}

// tanh(x) = sign(x) * (e - 1)/(e + 1), e = 2^(2|x|*log2 e)   (UNCHANGED - bitwise)
__device__ __forceinline__ float tanh_fast(float x) {
    float ax = fabsf(x);
    float z  = fminf(ax * 2.8853900817779268f, 30.0f);
    float e  = fast_exp2(z);
    float r  = (e - 1.0f) * fast_rcp(e + 1.0f);
    return x < 0.0f ? -r : r;
}

__device__ __forceinline__ float sigmoid_fast(float x) {
    float z = fminf(fmaxf(-x * 1.4426950408889634f, -60.0f), 60.0f);
    float e = fast_exp2(z);
    return fast_rcp(1.0f + e);
}

// R8 structure (best: 445 cyc/step = modeled floor 443) with the last safe
// shavings:
//  - both per-chunk __syncthreads removed: single wave + in-order DS pipe
//    means the fc reads queue behind step 63's write and next chunk's writes
//    queue behind the fc reads; "memory" clobbers on the asm DS ops stop the
//    compiler from reordering C-level hbuf loads across them. The barriers
//    only added a full vm/lgkm drain per chunk.
//  - a23 chain seeded with v_pk_mul_f32 (first term) instead of zero-init +
//    pk_fma: removes the pair zero-init. fma(w,h,+0) and w*h differ only when
//    w*h == -0 (then fma gives +0), and a ±0 a23 is absorbed unchanged by the
//    final combine adds -> output-identical.

#define RD(V, O) asm volatile("ds_read_b128 %0, %1 offset:" #O \
                              : "=v"(V) : "v"(rdaddr))

#define PKV(ACC, W2, H2) asm volatile("v_pk_fma_f32 %0, %1, %2, %0" \
                                      : "+v"(ACC) : "v"(W2), "v"(H2))

#define PKM(ACC, W2, H2) asm volatile("v_pk_mul_f32 %0, %1, %2" \
                                      : "=v"(ACC) : "v"(W2), "v"(H2))

#define LO(V) (*(const float2*)&(V))
#define HI(V) (*((const float2*)&(V) + 1))

#define WAITSB(N) do {                                            \
    asm volatile("s_waitcnt lgkmcnt(" #N ")" ::: "memory");       \
    __builtin_amdgcn_sched_barrier(0);                            \
} while (0)

// Wait math (in-order DS pipe): outstanding at WAITSB(12) = prev write +
// 16 reads; <=12 left => write + reads t0..t3 retired — exactly what group 0
// consumes. Groups 1-3 analogous at 8/4/0.
#define STEP(R_) do {                                                        \
    float4 t0,t1,t2,t3,t4,t5,t6,t7,t8,t9,tA,tB,tC,tD,tE,tF;                  \
    RD(t0, 0);   RD(t1, 16);  RD(t2, 32);  RD(t3, 48);                       \
    RD(t4, 64);  RD(t5, 80);  RD(t6, 96);  RD(t7, 112);                      \
    RD(t8, 128); RD(t9, 144); RD(tA, 160); RD(tB, 176);                      \
    RD(tC, 192); RD(tD, 208); RD(tE, 224); RD(tF, 240);                      \
    float xv = bcast_lane(xcur, R_);                                         \
    float2 a01 = make_float2(fmaf(wih, xv, bias), 0.0f);                     \
    float2 a23;                                                              \
    WAITSB(12);                                                              \
    PKV(a01, wpair[0], LO(t0));  PKM(a23, wpair[1],  HI(t0));                \
    PKV(a01, wpair[2], LO(t1));  PKV(a23, wpair[3],  HI(t1));                \
    PKV(a01, wpair[4], LO(t2));  PKV(a23, wpair[5],  HI(t2));                \
    PKV(a01, wpair[6], LO(t3));  PKV(a23, wpair[7],  HI(t3));                \
    WAITSB(8);                                                               \
    PKV(a01, wpair[8],  LO(t4)); PKV(a23, wpair[9],  HI(t4));                \
    PKV(a01, wpair[10], LO(t5)); PKV(a23, wpair[11], HI(t5));                \
    PKV(a01, wpair[12], LO(t6)); PKV(a23, wpair[13], HI(t6));                \
    PKV(a01, wpair[14], LO(t7)); PKV(a23, wpair[15], HI(t7));                \
    WAITSB(4);                                                               \
    PKV(a01, wpair[16], LO(t8)); PKV(a23, wpair[17], HI(t8));                \
    PKV(a01, wpair[18], LO(t9)); PKV(a23, wpair[19], HI(t9));                \
    PKV(a01, wpair[20], LO(tA)); PKV(a23, wpair[21], HI(tA));                \
    PKV(a01, wpair[22], LO(tB)); PKV(a23, wpair[23], HI(tB));                \
    WAITSB(0);                                                               \
    PKV(a01, wpair[24], LO(tC)); PKV(a23, wpair[25], HI(tC));                \
    PKV(a01, wpair[26], LO(tD)); PKV(a23, wpair[27], HI(tD));                \
    PKV(a01, wpair[28], LO(tE)); PKV(a23, wpair[29], HI(tE));                \
    PKV(a01, wpair[30], LO(tF)); PKV(a23, wpair[31], HI(tF));                \
    float aa = (a01.x + a01.y) + (a23.x + a23.y);                            \
    float hnew = tanh_fast(aa);                                              \
    asm volatile("ds_write_b32 %0, %1" :: "v"(wraddr), "v"(hnew) : "memory");\
} while (0)

__global__ __launch_bounds__(64) void rnn_floor_kernel(
    const float* __restrict__ x,      // [B, S]
    const float* __restrict__ W_ih,   // [H, 1]
    const float* __restrict__ b_ih,   // [H]
    const float* __restrict__ W_hh,   // [H, H]
    const float* __restrict__ b_hh,   // [H]
    const float* __restrict__ fc_w,   // [2, H]
    const float* __restrict__ fc_b,   // [2]
    float* __restrict__ out)          // [B]
{
    __shared__ float hbuf[CHUNK * ROWSTRIDE];   // 64 rows of h history

    const int lane = threadIdx.x;               // == hidden index i
    const int b    = blockIdx.x;
    const float* xrow = x + (size_t)b * SLEN;

    // Lane i holds W_hh row i as float2 pairs:
    //   wpair[2q]   = (w[4q],   w[4q+1])  -> a01 chain   (q = 0..15)
    //   wpair[2q+1] = (w[4q+2], w[4q+3])  -> a23 chain
    float2 wpair[32];
    #pragma unroll
    for (int q = 0; q < 16; ++q) {
        float4 t = ((const float4*)(W_hh + lane * HID))[q];
        wpair[2*q]   = make_float2(t.x, t.y);
        wpair[2*q+1] = make_float2(t.z, t.w);
    }
    const float wih  = W_ih[lane];
    const float bias = b_ih[lane] + b_hh[lane];
    const float fcb0 = fc_b[0], fcb1 = fc_b[1];

    float num = 0.0f, den = 0.0f;

    // LDS byte addresses (low 32 bits of a generic LDS pointer = byte offset)
    const uint32_t hb    = (uint32_t)(uintptr_t)&hbuf[0];
    const uint32_t lane4 = (uint32_t)(lane * 4);

    // h_{-1} = 0 -> row 63 (read by step r=0 of chunk 0); ordered with asm reads
    {
        float z0 = 0.0f;
        uint32_t ia = hb + 63 * ROWBYTES + lane4;
        asm volatile("ds_write_b32 %0, %1" :: "v"(ia), "v"(z0) : "memory");
    }

    float xv_next = xrow[lane];     // chunk 0's x values (one per lane)

    #pragma unroll 1
    for (int c = 0; c < NCHUNK; ++c) {
        float xcur = xv_next;
        // prefetch next chunk's x (off critical path; clamp index for last chunk)
        int nidx = (c + 1 < NCHUNK) ? (c + 1) * CHUNK + lane : lane;
        xv_next = xrow[nidx];

        uint32_t rdaddr = hb + 63 * ROWBYTES;   // step 0 reads row 63
        uint32_t wraddr = hb + lane4;           // step 0 writes row 0

        #pragma unroll 4
        for (int r = 0; r < CHUNK; ++r) {
            STEP(r);
            rdaddr = wraddr - lane4;            // next step reads row r
            wraddr += ROWBYTES;
        }
        // NO __syncthreads: single wave + in-order DS pipe. The fc reads
        // below are issued after step 63's ds_write in program order, so the
        // DS pipe serves them after it; the compiler's own lgkmcnt waits
        // cover the data dependences, and "memory" clobbers on the asm DS
        // ops prevent any C-level load from being hoisted/sunk across.

        // fc head for the chunk: lane processes row `lane` (1 timestep per lane)
        {
            const float4* rp = (const float4*)(hbuf + lane * ROWSTRIDE);
            float d0 = 0.f, d1 = 0.f;
            #pragma unroll
            for (int q = 0; q < 16; ++q) {
                float4 hv = rp[q];
                float4 f0 = ((const float4*)fc_w)[q];          // uniform -> s_load
                float4 f1 = ((const float4*)(fc_w + HID))[q];
                d0 += hv.x * f0.x + hv.y * f0.y + hv.z * f0.z + hv.w * f0.w;
                d1 += hv.x * f1.x + hv.y * f1.y + hv.z * f1.z + hv.w * f1.w;
            }
            float sel = sigmoid_fast(d0 + fcb0);
            float sco = sigmoid_fast(d1 + fcb1);
            num = fmaf(sco, sel, num);
            den += sel;
        }
        // NO __syncthreads here either: next chunk's ds_writes are issued
        // after the fc reads in program order -> in-order DS pipe preserves
        // read-before-overwrite.
    }

    // Final cross-lane reduction of (num, den)
    #pragma unroll
    for (int off = 32; off > 0; off >>= 1) {
        num += __shfl_down(num, off);
        den += __shfl_down(den, off);
    }
    if (lane == 0) out[b] = num / den;
}

extern "C" void kernel_launch(void* const* d_in, const int* in_sizes, int n_in,
                              void* d_out, int out_size, void* d_ws, size_t ws_size,
                              hipStream_t stream) {
    const float* x    = (const float*)d_in[0];
    const float* W_ih = (const float*)d_in[1];
    const float* b_ih = (const float*)d_in[2];
    const float* W_hh = (const float*)d_in[3];
    const float* b_hh = (const float*)d_in[4];
    const float* fc_w = (const float*)d_in[5];
    const float* fc_b = (const float*)d_in[6];
    float* out = (float*)d_out;

    rnn_floor_kernel<<<BATCH, 64, 0, stream>>>(x, W_ih, b_ih, W_hh, b_hh,
                                               fc_w, fc_b, out);
}